// Round 12
// baseline (88.016 us; speedup 1.0000x reference)
//
#include <hip/hip_runtime.h>
#include <hip/hip_bf16.h>
#include <math.h>

#define BS 8192
#define D 128
#define NROWS 16384               // 2*BS
#define NCHUNK 32                 // 32 col-chunks of 16 = 512 cols per tile-job
#define NJOBS 3136                // 2048 noise-half + 1088 f-upper/straddle

typedef __bf16 bf16x8 __attribute__((ext_vector_type(8)));
typedef float f32x4 __attribute__((ext_vector_type(4)));

#define SQRT_LOG2E 1.2011224087864498f
#define LN2F 0.6931471805599453f

#if __has_builtin(__builtin_amdgcn_exp2f)
#define EXP2F(x) __builtin_amdgcn_exp2f(x)
#else
#define EXP2F(x) exp2f(x)
#endif

// Layout of catT ("chunk-tiled kc-major"): byte addr of (row, k) =
//   (row>>4)*4096 + (k>>3)*256 + (row&15)*16 + (k&7)*2
// -> any 16-row x K=128 tile is one contiguous 4 KiB chunk; a wave B-frag
//    load (lanes: l4=kc, l15=col) at lane*16 is contiguous 1 KiB.

// Kernel 1: row norms + pre-scaled bf16 conversion into catT.
// Rows scaled by sqrt(log2e)/||row|| so MFMA yields cos_sim*log2e directly.
__global__ __launch_bounds__(256) void nrm_cvt(const float* __restrict__ f,
                                               const float* __restrict__ noise,
                                               char* __restrict__ catT) {
  const int lane = threadIdx.x & 63;
  const int wv = threadIdx.x >> 6;
  const int row = blockIdx.x * 4 + wv;
  const float* src = (row < BS) ? (noise + (size_t)row * D) : (f + (size_t)(row - BS) * D);
  float2 v = ((const float2*)src)[lane];   // k = 2*lane, 2*lane+1  (same kc cell)
  float ss = v.x * v.x + v.y * v.y;
#pragma unroll
  for (int m = 1; m <= 32; m <<= 1) ss += __shfl_xor(ss, m, 64);
  float s = SQRT_LOG2E / sqrtf(ss);
  float2 sv;
  sv.x = v.x * s;
  sv.y = v.y * s;
  __hip_bfloat162 b2 = __float22bfloat162_rn(sv);
  char* dst = catT + ((size_t)(row >> 4) << 12) + ((lane >> 2) << 8) +
              ((row & 15) << 4) + ((lane & 3) << 2);
  *(__hip_bfloat162*)dst = b2;
}

// Kernel 2: fused GEMM + exp2 + row/col-sum with f.f^T TRIANGLE SYMMETRY.
// Work tiles (64 rows x 512 cols), one per wave (4-wave blocks, no barriers,
// no LDS, reg double-buffer — R8 structure, best measured):
//   jobs [0,2048):  noise half, tile (rg = j>>4, cs = j&15). Row-sums only;
//                   pos-diagonal excluded + stored.
//   jobs [2048,..): f.f^T upper triangle, cs-strip enumeration inverted in
//                   closed form. Tiles with rg < 8cs are fully upper: emit
//                   row-sums AND column-sums (col j's lower-half sum for the
//                   symmetric rows). Tiles rg in [8cs, 8cs+8) straddle the
//                   diagonal: mask col>row (also excludes self-sim).
//   Strictly-lower tiles are NEVER computed: -23.4% MFMA/exp/load work.
// Column sums: per chunk each lane holds 16 exps of ONE column; tree-sum +
// shfl over l4 -> 64-row colsum; store to colneg[rg][col] (unique writer,
// deterministic, no atomics).
__global__ __launch_bounds__(256) void infonce_main(
    const char* __restrict__ catT,
    float* __restrict__ wsN,     // [16][BS] noise-half rowsum partials
    float* __restrict__ wsF,     // [16][BS] f-half rowsum partials
    float* __restrict__ colneg,  // [128][BS] f-half colsum partials
    float* __restrict__ ws_pos) {
  const int tid = threadIdx.x;
  const int lane = tid & 63;
  const int w = tid >> 6;
  const int l15 = lane & 15, l4 = lane >> 4;
  const int jid = blockIdx.x * 4 + w;

  int rg, cs;
  bool fh;
  if (jid < 2048) {
    rg = jid >> 4;
    cs = jid & 15;
    fh = false;
  } else {
    const int t = jid - 2048;
    if (t >= 960) {
      cs = 15;
      rg = t - 960;
    } else {
      // invert cumulative 4c(c+1) <= t < 4(c+1)(c+2); fp32 sqrt + int fixup
      int c = (int)((sqrtf((float)t + 1.0f) - 1.0f) * 0.5f);
      while (4 * (c + 1) * (c + 2) <= t) ++c;
      while (c > 0 && 4 * c * (c + 1) > t) --c;
      cs = c;
      rg = t - 4 * c * (c + 1);
    }
    fh = true;
  }
  const int growbase = rg * 64;                    // f row ids
  const int colf0 = cs * 512;                      // local col base
  const int col0cat = fh ? (BS + colf0) : colf0;   // cat col base
  const bool strad = fh && (rg >= 8 * cs);

  // A fragments: 64 f-rows, all of K=128 (64 VGPRs), contiguous loads.
  bf16x8 a[4][4];
  {
    const char* ab = catT + (size_t)(BS + growbase) * 256 + lane * 16;
#pragma unroll
    for (int rf = 0; rf < 4; rf++)
#pragma unroll
      for (int kk = 0; kk < 4; kk++)
        a[rf][kk] = *(const bf16x8*)(ab + rf * 4096 + kk * 1024);
  }

  float rowsum[16];
#pragma unroll
  for (int i = 0; i < 16; i++) rowsum[i] = 0.f;

  const char* bl = catT + (size_t)col0cat * 256 + lane * 16;

  auto loadB = [&](bf16x8* b, int ch) {
    const char* p = bl + (size_t)ch * 4096;
#pragma unroll
    for (int kk = 0; kk < 4; kk++) b[kk] = *(const bf16x8*)(p + kk * 1024);
  };

  bf16x8 bb[2][4];
  loadB(bb[0], 0);

  const f32x4 z = {0.f, 0.f, 0.f, 0.f};

#pragma unroll 2
  for (int ch = 0; ch < NCHUNK; ++ch) {
    const int cu = ch & 1;
    if (ch + 1 < NCHUNK) loadB(bb[cu ^ 1], ch + 1);

    f32x4 acc[4];
#pragma unroll
    for (int rf = 0; rf < 4; rf++)
      acc[rf] = __builtin_amdgcn_mfma_f32_16x16x32_bf16(a[rf][0], bb[cu][0], z, 0, 0, 0);
#pragma unroll
    for (int kk = 1; kk < 4; kk++)
#pragma unroll
      for (int rf = 0; rf < 4; rf++)
        acc[rf] = __builtin_amdgcn_mfma_f32_16x16x32_bf16(a[rf][kk], bb[cu][kk], acc[rf], 0, 0, 0);

    const int c0 = colf0 + ch * 16;  // local col of this chunk
    if (!fh) {
      // noise half: rowsum only; exclude + store pos on diagonal chunks
      const bool dPos = ((c0 & ~63) == growbase);
      if (!dPos) {
#pragma unroll
        for (int rf = 0; rf < 4; rf++)
#pragma unroll
          for (int r = 0; r < 4; r++) rowsum[rf * 4 + r] += EXP2F(acc[rf][r]);
      } else {
#pragma unroll
        for (int rf = 0; rf < 4; rf++)
#pragma unroll
          for (int r = 0; r < 4; r++) {
            const int grow = growbase + rf * 16 + l4 * 4 + r;
            const int gcol = c0 + l15;
            const float v = acc[rf][r];
            const bool ex = (gcol == grow);
            if (ex) ws_pos[grow] = v;  // sim_pos * log2e
            rowsum[rf * 4 + r] += ex ? 0.f : EXP2F(v);
          }
      }
    } else {
      // f half (upper/straddle): rowsum + colsum; straddle masks col>row
      float e_[16];
      if (!strad) {
#pragma unroll
        for (int rf = 0; rf < 4; rf++)
#pragma unroll
          for (int r = 0; r < 4; r++) e_[rf * 4 + r] = EXP2F(acc[rf][r]);
      } else {
        const int gcol = c0 + l15;
#pragma unroll
        for (int rf = 0; rf < 4; rf++)
#pragma unroll
          for (int r = 0; r < 4; r++) {
            const int grow = growbase + rf * 16 + l4 * 4 + r;
            e_[rf * 4 + r] = (gcol > grow) ? EXP2F(acc[rf][r]) : 0.f;
          }
      }
#pragma unroll
      for (int s = 0; s < 16; s++) rowsum[s] += e_[s];
      // per-lane column partial (this lane's 16 rows of column c0+l15)
      float csum = ((e_[0] + e_[1]) + (e_[2] + e_[3])) +
                   ((e_[4] + e_[5]) + (e_[6] + e_[7])) +
                   ((e_[8] + e_[9]) + (e_[10] + e_[11])) +
                   ((e_[12] + e_[13]) + (e_[14] + e_[15]));
      csum += __shfl_xor(csum, 16, 64);
      csum += __shfl_xor(csum, 32, 64);  // full 64-row colsum (all l4 groups)
      if (l4 == 0) colneg[(size_t)rg * BS + c0 + l15] = csum;
    }
  }

  // reduce rowsums across the 16 lanes (l15) sharing each row
#pragma unroll
  for (int s = 0; s < 16; s++) {
    float v = rowsum[s];
    v += __shfl_xor(v, 1, 64);
    v += __shfl_xor(v, 2, 64);
    v += __shfl_xor(v, 4, 64);
    v += __shfl_xor(v, 8, 64);
    rowsum[s] = v;
  }
  if (l15 == 0) {
    float* dst = (fh ? wsF : wsN) + (size_t)cs * BS + growbase;
#pragma unroll
    for (int rf = 0; rf < 4; rf++)
#pragma unroll
      for (int r = 0; r < 4; r++) dst[rf * 16 + l4 * 4 + r] = rowsum[rf * 4 + r];
  }
}

// Kernel 3a: combine partials, per-row loss, 32-block partial sums.
// Valid partial sets per row i: all 16 noise parts; f rowsum parts cs >= i>>9;
// colneg planes rg < 8*(i>>9)+8 (exactly the kept tiles of i's col-strip).
__global__ __launch_bounds__(256) void finalize1(const float* __restrict__ wsN,
                                                 const float* __restrict__ wsF,
                                                 const float* __restrict__ colneg,
                                                 const float* __restrict__ ws_pos,
                                                 float* __restrict__ partial) {
  const int row = blockIdx.x * 256 + threadIdx.x;
  float neg = 0.f;
#pragma unroll
  for (int p = 0; p < 16; p++) neg += wsN[(size_t)p * BS + row];
  for (int cx = row >> 9; cx < 16; cx++) neg += wsF[(size_t)cx * BS + row];
  const int nrg = 8 * (row >> 9) + 8;
  for (int rg = 0; rg < nrg; rg++) neg += colneg[(size_t)rg * BS + row];
  // loss = log(neg_sum + eps) - sim_pos ; sim_pos = (sim*log2e)*ln2
  float local = logf(neg + 1e-6f) - ws_pos[row] * LN2F;
#pragma unroll
  for (int m = 1; m <= 32; m <<= 1) local += __shfl_xor(local, m, 64);
  __shared__ float red[4];
  if ((threadIdx.x & 63) == 0) red[threadIdx.x >> 6] = local;
  __syncthreads();
  if (threadIdx.x == 0) partial[blockIdx.x] = red[0] + red[1] + red[2] + red[3];
}

// Kernel 3b: final mean over the 32 block partials.
__global__ void finalize2(const float* __restrict__ partial, float* __restrict__ out) {
  float v = ((int)threadIdx.x < 32) ? partial[threadIdx.x] : 0.f;
#pragma unroll
  for (int m = 1; m <= 32; m <<= 1) v += __shfl_xor(v, m, 64);
  if (threadIdx.x == 0) out[0] = v * (1.f / BS);
}

extern "C" void kernel_launch(void* const* d_in, const int* in_sizes, int n_in,
                              void* d_out, int out_size, void* d_ws, size_t ws_size,
                              hipStream_t stream) {
  const float* f = (const float*)d_in[0];
  const float* noise = (const float*)d_in[1];
  char* ws = (char*)d_ws;
  char* catT = ws;                                       // 4 MiB (chunk-tiled)
  float* ws_pos = (float*)(ws + (size_t)NROWS * D * 2);  // 32 KiB
  float* wsN = ws_pos + BS;                              // 512 KiB
  float* wsF = wsN + (size_t)16 * BS;                    // 512 KiB
  float* colneg = wsF + (size_t)16 * BS;                 // 4 MiB
  float* partial = colneg + (size_t)128 * BS;            // 128 B

  nrm_cvt<<<NROWS / 4, 256, 0, stream>>>(f, noise, catT);
  infonce_main<<<NJOBS / 4, 256, 0, stream>>>(catT, wsN, wsF, colneg, ws_pos);
  finalize1<<<BS / 256, 256, 0, stream>>>(wsN, wsF, colneg, ws_pos, partial);
  finalize2<<<1, 64, 0, stream>>>(partial, (float*)d_out);
}

// Round 13
// 40.593 us; speedup vs baseline: 2.1683x; 2.1683x over previous
//
#include <hip/hip_runtime.h>
#include <hip/hip_bf16.h>
#include <math.h>

#define BS 8192
#define D 128
#define NROWS 16384               // 2*BS
#define COLS_PER_BLOCK 512
#define NCHUNK (COLS_PER_BLOCK / 16)      // 32 col-chunks of 16
#define NSPLIT (NROWS / COLS_PER_BLOCK)   // 32 col-splits
#define NPART NSPLIT                      // 32 partial buffers

typedef int i32x8 __attribute__((ext_vector_type(8)));
typedef float f32x4 __attribute__((ext_vector_type(4)));

#define LN2F 0.6931471805599453f
// store scale: elements written as x * 2^4 * sqrt(log2e) / ||row||; HW E8M0
// scale 2^-4 on A and B restores acc = sim * log2e exactly (powers of 2).
#define STORE_SCALE 19.217958569050494f   // 16 * 1.2011224087864498
#define E8M0_M4 123                       // 2^(123-127) = 2^-4

#if __has_builtin(__builtin_amdgcn_exp2f)
#define EXP2F(x) __builtin_amdgcn_exp2f(x)
#else
#define EXP2F(x) exp2f(x)
#endif

// Layout of catF (fp8, "16-row-group tiled"): byte addr of (row, k) =
//   (row>>4)*2048 + (k>>5)*512 + (row&15)*32 + (k&31)
// -> a 16-row x K=128 group is one contiguous 2 KiB cell; an MFMA fragment
//    (lanes: l15=row/col, l4=k-block-of-32) is lane 32B at l4*512+l15*32 —
//    the wave's 64x32B = the whole 2 KiB cell, fully coalesced.

// Kernel 1: row norms + scaled fp8(e4m3) conversion into catF.
__global__ __launch_bounds__(256) void nrm_cvt(const float* __restrict__ f,
                                               const float* __restrict__ noise,
                                               char* __restrict__ catF) {
  const int lane = threadIdx.x & 63;
  const int wv = threadIdx.x >> 6;
  const int row = blockIdx.x * 4 + wv;
  const float* src = (row < BS) ? (noise + (size_t)row * D) : (f + (size_t)(row - BS) * D);
  float2 v = ((const float2*)src)[lane];   // k = 2*lane, 2*lane+1 (same 32-cell)
  float ss = v.x * v.x + v.y * v.y;
#pragma unroll
  for (int m = 1; m <= 32; m <<= 1) ss += __shfl_xor(ss, m, 64);
  const float s = STORE_SCALE / sqrtf(ss);
  // pack 2 floats -> 2 OCP e4m3 bytes (low 16 bits)
  const int packed = __builtin_amdgcn_cvt_pk_fp8_f32(v.x * s, v.y * s, 0, false);
  char* dst = catF + ((size_t)(row >> 4) << 11) + ((lane >> 4) << 9) +
              ((row & 15) << 5) + ((lane & 15) << 1);
  *(unsigned short*)dst = (unsigned short)(packed & 0xffff);
}

// Kernel 2: fused GEMM + exp2 + row-sum, MX-FP8 K=128: ONE
// mfma_scale_f32_16x16x128_f8f6f4 per 16x16 output tile (replaces 16 bf16
// MFMAs + 4 loads per chunk with 1 MFMA + 2 loads). R8 structure otherwise:
// 4-wave blocks, no LDS, no barriers, register double-buffered B.
__global__ __launch_bounds__(256) void infonce_main(
    const char* __restrict__ catF,
    float* __restrict__ ws_neg, float* __restrict__ ws_pos) {
  const int tid = threadIdx.x;
  const int lane = tid & 63;
  const int w = tid >> 6;
  const int l15 = lane & 15, l4 = lane >> 4;
  const int nb = blockIdx.x, mb = blockIdx.y;
  const int growbase = mb * 256 + w * 64;
  const int col0 = nb * COLS_PER_BLOCK;
  const int lbase = l4 * 512 + l15 * 32;

  // A fragments: 64 f-rows x K=128 fp8 (32 VGPRs total)
  i32x8 a[4];
  {
    const char* ab = catF + ((size_t)((BS + growbase) >> 4) << 11) + lbase;
#pragma unroll
    for (int rf = 0; rf < 4; rf++) a[rf] = *(const i32x8*)(ab + rf * 2048);
  }

  f32x4 rs[4];
  const f32x4 z = {0.f, 0.f, 0.f, 0.f};
#pragma unroll
  for (int rf = 0; rf < 4; rf++) rs[rf] = z;

  const char* bl = catF + ((size_t)(col0 >> 4) << 11) + lbase;
  i32x8 bb[2];
  bb[0] = *(const i32x8*)(bl);

#pragma unroll
  for (int ch = 0; ch < NCHUNK; ++ch) {
    const int cu = ch & 1;  // compile-time under full unroll
    if (ch + 1 < NCHUNK) bb[cu ^ 1] = *(const i32x8*)(bl + (size_t)(ch + 1) * 2048);

    f32x4 acc[4];
#pragma unroll
    for (int rf = 0; rf < 4; rf++)
      acc[rf] = __builtin_amdgcn_mfma_scale_f32_16x16x128_f8f6f4(
          a[rf], bb[cu], z, 0 /*A=fp8*/, 0 /*B=fp8*/,
          0, E8M0_M4, 0, E8M0_M4);

    // epilogue: acc = sim*log2e -> exp2, accumulate row sums, excise diagonals.
    const int c0 = col0 + ch * 16;
    const bool dPos = ((c0 & ~63) == growbase);          // cols == f-row ids
    const bool dSelf = (((c0 - BS) & ~63) == growbase);  // cols == i+bs
    if (!dPos && !dSelf) {
#pragma unroll
      for (int rf = 0; rf < 4; rf++) {
        f32x4 e;
#pragma unroll
        for (int r = 0; r < 4; r++) e[r] = EXP2F(acc[rf][r]);
        rs[rf] += e;  // f32x4 add -> v_pk_add_f32 pair
      }
    } else {
#pragma unroll
      for (int rf = 0; rf < 4; rf++)
#pragma unroll
        for (int r = 0; r < 4; r++) {
          const int grow = growbase + rf * 16 + l4 * 4 + r;
          const int gcol = c0 + l15;
          const float v = acc[rf][r];
          const bool ex = dPos ? (gcol == grow) : (gcol == grow + BS);
          if (dPos && gcol == grow) ws_pos[grow] = v;  // sim_pos * log2e
          rs[rf][r] += ex ? 0.f : EXP2F(v);
        }
    }
  }

  // reduce rowsums across the 16 lanes (l15) sharing each row
  float rowsum[16];
#pragma unroll
  for (int rf = 0; rf < 4; rf++)
#pragma unroll
    for (int r = 0; r < 4; r++) {
      float v = rs[rf][r];
      v += __shfl_xor(v, 1, 64);
      v += __shfl_xor(v, 2, 64);
      v += __shfl_xor(v, 4, 64);
      v += __shfl_xor(v, 8, 64);
      rowsum[rf * 4 + r] = v;
    }
  if (l15 == 0) {
    float* dst = ws_neg + (size_t)nb * BS + growbase;
#pragma unroll
    for (int rf = 0; rf < 4; rf++)
#pragma unroll
      for (int r = 0; r < 4; r++) dst[rf * 16 + l4 * 4 + r] = rowsum[rf * 4 + r];
  }
}

// Kernel 3a: per-row loss, 32-block partial sums.
__global__ __launch_bounds__(256) void finalize1(const float* __restrict__ ws_neg,
                                                 const float* __restrict__ ws_pos,
                                                 float* __restrict__ partial) {
  const int row = blockIdx.x * 256 + threadIdx.x;
  float neg = 0.f;
#pragma unroll
  for (int p = 0; p < NPART; p++) neg += ws_neg[(size_t)p * BS + row];
  // loss = log(neg_sum + eps) - sim_pos ; sim_pos = (sim*log2e)*ln2
  float local = logf(neg + 1e-6f) - ws_pos[row] * LN2F;
#pragma unroll
  for (int m = 1; m <= 32; m <<= 1) local += __shfl_xor(local, m, 64);
  __shared__ float red[4];
  if ((threadIdx.x & 63) == 0) red[threadIdx.x >> 6] = local;
  __syncthreads();
  if (threadIdx.x == 0) partial[blockIdx.x] = red[0] + red[1] + red[2] + red[3];
}

// Kernel 3b: final mean over the 32 block partials.
__global__ void finalize2(const float* __restrict__ partial, float* __restrict__ out) {
  float v = ((int)threadIdx.x < 32) ? partial[threadIdx.x] : 0.f;
#pragma unroll
  for (int m = 1; m <= 32; m <<= 1) v += __shfl_xor(v, m, 64);
  if (threadIdx.x == 0) out[0] = v * (1.f / BS);
}

extern "C" void kernel_launch(void* const* d_in, const int* in_sizes, int n_in,
                              void* d_out, int out_size, void* d_ws, size_t ws_size,
                              hipStream_t stream) {
  const float* f = (const float*)d_in[0];
  const float* noise = (const float*)d_in[1];
  char* ws = (char*)d_ws;
  char* catF = ws;                                       // 2 MiB (fp8 tiled)
  float* ws_pos = (float*)(ws + (size_t)NROWS * D);      // 32 KiB
  float* ws_neg = ws_pos + BS;                           // 1 MiB
  float* partial = ws_neg + (size_t)NPART * BS;          // 128 B

  nrm_cvt<<<NROWS / 4, 256, 0, stream>>>(f, noise, catF);
  dim3 grid(NSPLIT, BS / 256);                           // 32 x 32 = 1024 blocks
  infonce_main<<<grid, 256, 0, stream>>>(catF, ws_neg, ws_pos);
  finalize1<<<BS / 256, 256, 0, stream>>>(ws_neg, ws_pos, partial);
  finalize2<<<1, 64, 0, stream>>>(partial, (float*)d_out);
}